// Round 2
// baseline (205.063 us; speedup 1.0000x reference)
//
#include <hip/hip_runtime.h>

#define AP_STRIDE 164                 // per-wire A stride (floats)
#define AP_TOTAL  (4*AP_STRIDE)       // 656
#define WS_SUMS   AP_TOTAL            // ws[656..663]: sum[4], sumsq[4]

// packed-triangular row offsets (row i holds j=i..15, padded to multiple of 4 floats)
static constexpr int ROWOFF[16] = {0,16,32,48,64,76,88,100,112,120,128,136,144,148,152,156};
static constexpr int ROWL4[16]  = {4,4,4,4,3,3,3,3,2,2,2,2,1,1,1,1};

// ---------------------------------------------------------------------------
// k_pre: build U (weights-only part of the circuit), then A_w = Re(phase * U^dag Z_w U),
// packed triangular with off-diagonal doubled. Also zero the sum accumulators.
// ---------------------------------------------------------------------------
__global__ void k_pre(const float* __restrict__ W, float* __restrict__ ws){
  __shared__ float Ur[16][16];   // Ur[k][col]
  __shared__ float Uim[16][16];
  const int t = threadIdx.x;

  for (int k = t; k < AP_TOTAL; k += 256) ws[k] = 0.f;
  if (t < 8) ws[WS_SUMS + t] = 0.f;

  if (t < 16){
    float re[16], im[16];
    #pragma unroll
    for (int i = 0; i < 16; i++){ re[i] = 0.f; im[i] = 0.f; }
    re[t] = 1.f;

    #pragma unroll
    for (int l = 0; l < 2; l++){
      #pragma unroll
      for (int w = 0; w < 4; w++){
        const int m = 8 >> w;
        const float* g = W + (l*4 + w)*3;
        {
          float th = 0.5f*g[0], c = cosf(th), s = sinf(th);
          #pragma unroll
          for (int i0 = 0; i0 < 16; i0++) if (!(i0 & m)){
            int i1 = i0 | m;
            float a0r=re[i0], a0i=im[i0], a1r=re[i1], a1i=im[i1];
            re[i0] = c*a0r + s*a1i;  im[i0] = c*a0i - s*a1r;
            re[i1] = c*a1r + s*a0i;  im[i1] = c*a1i - s*a0r;
          }
        }
        {
          float th = 0.5f*g[1], c = cosf(th), s = sinf(th);
          #pragma unroll
          for (int i0 = 0; i0 < 16; i0++) if (!(i0 & m)){
            int i1 = i0 | m;
            float a0r=re[i0], a0i=im[i0], a1r=re[i1], a1i=im[i1];
            re[i0] = c*a0r - s*a1r;  im[i0] = c*a0i - s*a1i;
            re[i1] = s*a0r + c*a1r;  im[i1] = s*a0i + c*a1i;
          }
        }
        {
          float th = 0.5f*g[2], c = cosf(th), s = sinf(th);
          #pragma unroll
          for (int i0 = 0; i0 < 16; i0++) if (!(i0 & m)){
            int i1 = i0 | m;
            float a0r=re[i0], a0i=im[i0], a1r=re[i1], a1i=im[i1];
            re[i0] = c*a0r + s*a0i;  im[i0] = c*a0i - s*a0r;
            re[i1] = c*a1r - s*a1i;  im[i1] = c*a1i + s*a1r;
          }
        }
      }
      #pragma unroll
      for (int w = 0; w < 4; w++){
        const int mc = 8 >> w, mt = 8 >> ((w+1)&3);
        float nr[16], ni[16];
        #pragma unroll
        for (int i = 0; i < 16; i++){
          int src = (i & mc) ? (i ^ mt) : i;
          nr[i] = re[src]; ni[i] = im[src];
        }
        #pragma unroll
        for (int i = 0; i < 16; i++){ re[i] = nr[i]; im[i] = ni[i]; }
      }
    }
    #pragma unroll
    for (int k = 0; k < 16; k++){ Ur[k][t] = re[k]; Uim[k][t] = im[k]; }
  }
  __syncthreads();

  {
    const int i = t >> 4, j = t & 15;
    if (i <= j){
      const int d = (__popc(i) - __popc(j)) & 3;
      #pragma unroll
      for (int w = 0; w < 4; w++){
        const int zm = 8 >> w;
        float mr = 0.f, mi = 0.f;
        #pragma unroll
        for (int k = 0; k < 16; k++){
          float z = (k & zm) ? -1.f : 1.f;
          float uir = Ur[k][i], uii = Uim[k][i];
          float ujr = Ur[k][j], uji = Uim[k][j];
          mr += z*(uir*ujr + uii*uji);
          mi += z*(uir*uji - uii*ujr);
        }
        float v = (d == 0) ? mr : (d == 1) ? -mi : (d == 2) ? -mr : mi;
        if (i != j) v *= 2.f;
        ws[w*AP_STRIDE + ROWOFF[i] + (j - i)] = v;
      }
    }
  }
}

// ---------------------------------------------------------------------------
// k_main: per block = 64 batch elements. Coalesced float4 loads -> register
// pooling partials -> LDS atomic combine (1 KB) -> circuit quadratic forms.
// No raw-x staging: LDS = ~4.4 KB, occupancy VGPR-bound.
// ---------------------------------------------------------------------------
__global__ __launch_bounds__(256, 4) void k_main(const float* __restrict__ x,
                                                 const float* __restrict__ Ap,
                                                 float* __restrict__ qout,
                                                 float* __restrict__ sums){
  __shared__ __align__(16) float Asm[AP_TOTAL];      // 2624 B
  __shared__ __align__(16) float pooled[256];        // 1 KB: [b][w]
  __shared__ float wred[4][8];
  const int t = threadIdx.x;
  const size_t base = (size_t)blockIdx.x * 64;

  // 9 coalesced float4 loads covering the chunk (64 rows x 36 float4)
  const float4* xg = (const float4*)(x + base*144);
  float4 v[9];
  #pragma unroll
  for (int k = 0; k < 9; k++) v[k] = xg[t + k*256];

  if (t < 64) *((float4*)&pooled[t*4]) = make_float4(0.f,0.f,0.f,0.f);
  for (int k = t; k < AP_TOTAL; k += 256) Asm[k] = Ap[k];
  __syncthreads();

  // pooling partials: float4 #p of row b; col-group cg = p%3 (0:left,1:split,2:right),
  // top half iff p<18. Incremental update: idx += 256 => p += 4 (mod 36), b += 7(+c), cg += 1 (mod 3)
  {
    int p = t % 36;
    int b = t - p;  b = (t) / 36;   // let compiler magic-div once
    p = t - b*36;
    int cg = p % 3;
    #pragma unroll
    for (int k = 0; k < 9; k++){
      float s01 = v[k].x + v[k].y, s23 = v[k].z + v[k].w;
      float all = s01 + s23;
      float L = (cg==0) ? all : ((cg==1) ? s01 : 0.f);
      float R = (cg==2) ? all : ((cg==1) ? s23 : 0.f);
      float* dst = &pooled[b*4 + ((p < 18) ? 0 : 2)];
      atomicAdd(dst,     L);
      atomicAdd(dst + 1, R);
      p += 4; b += 7;
      if (p >= 36){ p -= 36; b += 1; }
      cg += 1; if (cg == 3) cg = 0;
    }
  }
  __syncthreads();

  const int bb = t >> 2, w = t & 3;

  // all 4 half-angles for this batch element (redundant x4 but register-only)
  float4 pv = *((const float4*)&pooled[bb*4]);
  const float inv = 1.f/72.f;                 // (sum/36)/2
  float a0 = pv.x*inv, a1 = pv.y*inv, a2 = pv.z*inv, a3 = pv.w*inv;
  float c0 = __cosf(a0), s0 = __sinf(a0);
  float c1 = __cosf(a1), s1 = __sinf(a1);
  float c2 = __cosf(a2), s2 = __sinf(a2);
  float c3 = __cosf(a3), s3 = __sinf(a3);

  // r_i = prod_w (bit(i,w) ? s_w : c_w), bit(i,w)=(i>>(3-w))&1 -- Kronecker build
  float t00=c0*c1, t01=c0*s1, t10=s0*c1, t11=s0*s1;
  float u00=c2*c3, u01=c2*s3, u10=s2*c3, u11=s2*s3;
  float r[20];
  r[ 0]=t00*u00; r[ 1]=t00*u01; r[ 2]=t00*u10; r[ 3]=t00*u11;
  r[ 4]=t01*u00; r[ 5]=t01*u01; r[ 6]=t01*u10; r[ 7]=t01*u11;
  r[ 8]=t10*u00; r[ 9]=t10*u01; r[10]=t10*u10; r[11]=t10*u11;
  r[12]=t11*u00; r[13]=t11*u01; r[14]=t11*u10; r[15]=t11*u11;
  r[16]=0.f; r[17]=0.f; r[18]=0.f; r[19]=0.f;

  // q_w = r^T A_w r (packed upper-tri, off-diag pre-doubled, zero pads)
  const float* Aw = Asm + w*AP_STRIDE;
  float q = 0.f;
  #pragma unroll
  for (int i = 0; i < 16; i++){
    float acc = 0.f;
    const float4* row4 = (const float4*)(Aw + ROWOFF[i]);
    #pragma unroll
    for (int mm = 0; mm < ROWL4[i]; mm++){
      float4 a = row4[mm];
      acc = fmaf(a.x, r[i + mm*4 + 0], acc);
      acc = fmaf(a.y, r[i + mm*4 + 1], acc);
      acc = fmaf(a.z, r[i + mm*4 + 2], acc);
      acc = fmaf(a.w, r[i + mm*4 + 3], acc);
    }
    q = fmaf(r[i], acc, q);
  }

  qout[base*4 + t] = q;                       // coalesced

  // per-wire sum/sumsq reduction (lane groups w, w+4, ..., w+60)
  float qs = q, q2 = q*q;
  #pragma unroll
  for (int off = 32; off >= 4; off >>= 1){
    qs += __shfl_down(qs, off, 64);
    q2 += __shfl_down(q2, off, 64);
  }
  const int lane = t & 63, wv = t >> 6;
  if (lane < 4){ wred[wv][lane] = qs; wred[wv][lane+4] = q2; }
  __syncthreads();
  if (t < 8){
    float s = wred[0][t] + wred[1][t] + wred[2][t] + wred[3][t];
    atomicAdd(&sums[t], s);
  }
}

// ---------------------------------------------------------------------------
// k_statsnorm: every thread recomputes scale/shift from the 8 global sums
// (broadcast loads), then normalizes one float4 of out in place.
// ---------------------------------------------------------------------------
__global__ __launch_bounds__(256) void k_statsnorm(float* __restrict__ out,
                                                   const float* __restrict__ sums,
                                                   const float* __restrict__ gamma,
                                                   const float* __restrict__ beta,
                                                   float invB){
  const int idx = blockIdx.x*256 + threadIdx.x;   // one batch element
  float sc[4], sh[4];
  #pragma unroll
  for (int w = 0; w < 4; w++){
    float mean  = sums[w]   * invB;
    float var   = sums[w+4] * invB - mean*mean;
    float scale = gamma[w] * rsqrtf(var + 1e-5f);
    sc[w] = scale;
    sh[w] = fmaf(-mean, scale, beta[w]);
  }
  float4* o4 = (float4*)out;
  float4 qv = o4[idx];
  qv.x = fmaf(qv.x, sc[0], sh[0]);
  qv.y = fmaf(qv.y, sc[1], sh[1]);
  qv.z = fmaf(qv.z, sc[2], sh[2]);
  qv.w = fmaf(qv.w, sc[3], sh[3]);
  o4[idx] = qv;
}

// ---------------------------------------------------------------------------
extern "C" void kernel_launch(void* const* d_in, const int* in_sizes, int n_in,
                              void* d_out, int out_size, void* d_ws, size_t ws_size,
                              hipStream_t stream){
  const float* x     = (const float*)d_in[0];
  const float* W     = (const float*)d_in[1];
  const float* gamma = (const float*)d_in[2];
  const float* beta  = (const float*)d_in[3];
  float* ws  = (float*)d_ws;
  float* out = (float*)d_out;
  const int B = in_sizes[0] / 144;

  k_pre<<<1, 256, 0, stream>>>(W, ws);
  k_main<<<B/64, 256, 0, stream>>>(x, ws, out, ws + WS_SUMS);
  k_statsnorm<<<B/256, 256, 0, stream>>>(out, ws + WS_SUMS, gamma, beta, 1.f/(float)B);
}

// Round 3
// 127.914 us; speedup vs baseline: 1.6031x; 1.6031x over previous
//
#include <hip/hip_runtime.h>

// A layout: triangular index n (i<=j), interleaved by wire: ws[n*4 + w], n in [0,136)
// off-diagonal entries pre-doubled. Sums: 8 replicas of 8 floats at ws[544..608).
#define WS_SUMS   544
#define N_REP     8

__device__ __forceinline__ constexpr int tri(int i, int j){
  return 16*i - (i*(i-1))/2 + (j - i);
}

// ---------------------------------------------------------------------------
// k_pre: build U (weights-only circuit), A_w = Re(phase * U^dag Z_w U),
// triangular-packed, wire-interleaved, off-diag doubled. Zero the sum slots.
// ---------------------------------------------------------------------------
__global__ void k_pre(const float* __restrict__ W, float* __restrict__ ws){
  __shared__ float Ur[16][16];
  __shared__ float Uim[16][16];
  const int t = threadIdx.x;

  if (t < N_REP*8) ws[WS_SUMS + t] = 0.f;

  if (t < 16){
    float re[16], im[16];
    #pragma unroll
    for (int i = 0; i < 16; i++){ re[i] = 0.f; im[i] = 0.f; }
    re[t] = 1.f;

    #pragma unroll
    for (int l = 0; l < 2; l++){
      #pragma unroll
      for (int w = 0; w < 4; w++){
        const int m = 8 >> w;
        const float* g = W + (l*4 + w)*3;
        {
          float th = 0.5f*g[0], c = cosf(th), s = sinf(th);
          #pragma unroll
          for (int i0 = 0; i0 < 16; i0++) if (!(i0 & m)){
            int i1 = i0 | m;
            float a0r=re[i0], a0i=im[i0], a1r=re[i1], a1i=im[i1];
            re[i0] = c*a0r + s*a1i;  im[i0] = c*a0i - s*a1r;
            re[i1] = c*a1r + s*a0i;  im[i1] = c*a1i - s*a0r;
          }
        }
        {
          float th = 0.5f*g[1], c = cosf(th), s = sinf(th);
          #pragma unroll
          for (int i0 = 0; i0 < 16; i0++) if (!(i0 & m)){
            int i1 = i0 | m;
            float a0r=re[i0], a0i=im[i0], a1r=re[i1], a1i=im[i1];
            re[i0] = c*a0r - s*a1r;  im[i0] = c*a0i - s*a1i;
            re[i1] = s*a0r + c*a1r;  im[i1] = s*a0i + c*a1i;
          }
        }
        {
          float th = 0.5f*g[2], c = cosf(th), s = sinf(th);
          #pragma unroll
          for (int i0 = 0; i0 < 16; i0++) if (!(i0 & m)){
            int i1 = i0 | m;
            float a0r=re[i0], a0i=im[i0], a1r=re[i1], a1i=im[i1];
            re[i0] = c*a0r + s*a0i;  im[i0] = c*a0i - s*a0r;
            re[i1] = c*a1r - s*a1i;  im[i1] = c*a1i + s*a1r;
          }
        }
      }
      #pragma unroll
      for (int w = 0; w < 4; w++){
        const int mc = 8 >> w, mt = 8 >> ((w+1)&3);
        float nr[16], ni[16];
        #pragma unroll
        for (int i = 0; i < 16; i++){
          int src = (i & mc) ? (i ^ mt) : i;
          nr[i] = re[src]; ni[i] = im[src];
        }
        #pragma unroll
        for (int i = 0; i < 16; i++){ re[i] = nr[i]; im[i] = ni[i]; }
      }
    }
    #pragma unroll
    for (int k = 0; k < 16; k++){ Ur[k][t] = re[k]; Uim[k][t] = im[k]; }
  }
  __syncthreads();

  {
    const int i = t >> 4, j = t & 15;
    if (i <= j){
      const int d = (__popc(i) - __popc(j)) & 3;
      const int n = tri(i, j);
      #pragma unroll
      for (int w = 0; w < 4; w++){
        const int zm = 8 >> w;
        float mr = 0.f, mi = 0.f;
        #pragma unroll
        for (int k = 0; k < 16; k++){
          float z = (k & zm) ? -1.f : 1.f;
          float uir = Ur[k][i], uii = Uim[k][i];
          float ujr = Ur[k][j], uji = Uim[k][j];
          mr += z*(uir*ujr + uii*uji);
          mi += z*(uir*uji - uii*ujr);
        }
        float v = (d == 0) ? mr : (d == 1) ? -mi : (d == 2) ? -mr : mi;
        if (i != j) v *= 2.f;
        ws[n*4 + w] = v;
      }
    }
  }
}

// ---------------------------------------------------------------------------
// k_main: one thread = one batch row. 36 float4 loads in 3 phases of 12
// (deep MLP), register-only pooling, SGPR-broadcast A, all 4 wires/thread,
// coalesced float4 q-store, shuffle reduction + replicated atomics.
// ---------------------------------------------------------------------------
__global__ __launch_bounds__(256) void k_main(const float* __restrict__ x,
                                              const float* __restrict__ A,
                                              float* __restrict__ qout,
                                              float* __restrict__ sums){
  __shared__ float wred[4][8];
  const int t = threadIdx.x;
  const size_t row = (size_t)blockIdx.x*256 + t;
  const float4* rp = (const float4*)(x + row*144);

  // pooling: quadrant sums, fully static mapping. float4 #p: img-row p/3 (top iff p<18),
  // col-group p%3 (0: all-left, 1: split, 2: all-right)
  float aTL = 0.f, aTR = 0.f, aBL = 0.f, aBR = 0.f;
  #pragma unroll
  for (int ph = 0; ph < 3; ph++){
    float4 buf[12];
    #pragma unroll
    for (int j = 0; j < 12; j++) buf[j] = rp[ph*12 + j];
    #pragma unroll
    for (int j = 0; j < 12; j++){
      const int p  = ph*12 + j;
      const int cg = p % 3;
      float s01 = buf[j].x + buf[j].y, s23 = buf[j].z + buf[j].w;
      float L = (cg == 0) ? (s01 + s23) : ((cg == 1) ? s01 : 0.f);
      float R = (cg == 2) ? (s01 + s23) : ((cg == 1) ? s23 : 0.f);
      if (p < 18){ aTL += L; aTR += R; } else { aBL += L; aBR += R; }
    }
  }

  // half-angles and cos/sin (wire order = pooled order: TL,TR,BL,BR)
  const float inv = 1.f/72.f;
  float s0,c0,s1,c1,s2,c2,s3,c3;
  __sincosf(aTL*inv, &s0, &c0);
  __sincosf(aTR*inv, &s1, &c1);
  __sincosf(aBL*inv, &s2, &c2);
  __sincosf(aBR*inv, &s3, &c3);

  // r_i = prod_w (bit(i,w) ? s_w : c_w), bit(i,w) = (i>>(3-w))&1
  float t00=c0*c1, t01=c0*s1, t10=s0*c1, t11=s0*s1;
  float u00=c2*c3, u01=c2*s3, u10=s2*c3, u11=s2*s3;
  float r[16];
  r[ 0]=t00*u00; r[ 1]=t00*u01; r[ 2]=t00*u10; r[ 3]=t00*u11;
  r[ 4]=t01*u00; r[ 5]=t01*u01; r[ 6]=t01*u10; r[ 7]=t01*u11;
  r[ 8]=t10*u00; r[ 9]=t10*u01; r[10]=t10*u10; r[11]=t10*u11;
  r[12]=t11*u00; r[13]=t11*u01; r[14]=t11*u10; r[15]=t11*u11;

  // q_w = sum_{i<=j} A_w[n(i,j)] * r_i r_j  -- A indices are wave-uniform
  // compile-time constants off a uniform pointer -> scalar loads (SGPR broadcast)
  float q0=0.f, q1=0.f, q2=0.f, q3=0.f;
  #pragma unroll
  for (int i = 0; i < 16; i++){
    #pragma unroll
    for (int j = i; j < 16; j++){
      const int n = tri(i, j);
      float pij = r[i]*r[j];
      q0 = fmaf(A[n*4+0], pij, q0);
      q1 = fmaf(A[n*4+1], pij, q1);
      q2 = fmaf(A[n*4+2], pij, q2);
      q3 = fmaf(A[n*4+3], pij, q3);
    }
  }

  ((float4*)qout)[row] = make_float4(q0, q1, q2, q3);   // coalesced 16B/lane

  // block reduction of sum/sumsq for the 4 wires
  float red[8] = {q0, q1, q2, q3, q0*q0, q1*q1, q2*q2, q3*q3};
  #pragma unroll
  for (int off = 32; off >= 1; off >>= 1){
    #pragma unroll
    for (int k = 0; k < 8; k++) red[k] += __shfl_down(red[k], off, 64);
  }
  const int lane = t & 63, wv = t >> 6;
  if (lane == 0){
    #pragma unroll
    for (int k = 0; k < 8; k++) wred[wv][k] = red[k];
  }
  __syncthreads();
  if (t < 8){
    float s = wred[0][t] + wred[1][t] + wred[2][t] + wred[3][t];
    atomicAdd(&sums[(blockIdx.x & (N_REP-1))*8 + t], s);
  }
}

// ---------------------------------------------------------------------------
// k_statsnorm: recompute scale/shift from the replicated sums (uniform scalar
// loads), then normalize one float4 of out per thread, in place.
// ---------------------------------------------------------------------------
__global__ __launch_bounds__(256) void k_statsnorm(float* __restrict__ out,
                                                   const float* __restrict__ sums,
                                                   const float* __restrict__ gamma,
                                                   const float* __restrict__ beta,
                                                   float invB){
  const int idx = blockIdx.x*256 + threadIdx.x;
  float sc[4], sh[4];
  #pragma unroll
  for (int w = 0; w < 4; w++){
    float s1 = 0.f, s2 = 0.f;
    #pragma unroll
    for (int rep = 0; rep < N_REP; rep++){
      s1 += sums[rep*8 + w];
      s2 += sums[rep*8 + 4 + w];
    }
    float mean  = s1 * invB;
    float var   = s2 * invB - mean*mean;
    float scale = gamma[w] * rsqrtf(var + 1e-5f);
    sc[w] = scale;
    sh[w] = fmaf(-mean, scale, beta[w]);
  }
  float4* o4 = (float4*)out;
  float4 qv = o4[idx];
  qv.x = fmaf(qv.x, sc[0], sh[0]);
  qv.y = fmaf(qv.y, sc[1], sh[1]);
  qv.z = fmaf(qv.z, sc[2], sh[2]);
  qv.w = fmaf(qv.w, sc[3], sh[3]);
  o4[idx] = qv;
}

// ---------------------------------------------------------------------------
extern "C" void kernel_launch(void* const* d_in, const int* in_sizes, int n_in,
                              void* d_out, int out_size, void* d_ws, size_t ws_size,
                              hipStream_t stream){
  const float* x     = (const float*)d_in[0];
  const float* W     = (const float*)d_in[1];
  const float* gamma = (const float*)d_in[2];
  const float* beta  = (const float*)d_in[3];
  float* ws  = (float*)d_ws;
  float* out = (float*)d_out;
  const int B = in_sizes[0] / 144;

  k_pre<<<1, 256, 0, stream>>>(W, ws);
  k_main<<<B/256, 256, 0, stream>>>(x, ws, out, ws + WS_SUMS);
  k_statsnorm<<<B/256, 256, 0, stream>>>(out, ws + WS_SUMS, gamma, beta, 1.f/(float)B);
}